// Round 1
// baseline (1608.205 us; speedup 1.0000x reference)
//
#include <hip/hip_runtime.h>

#define T_TOK 4096
#define H_DIM 2048
#define F_DIM 4096
#define E_NUM 8

typedef __attribute__((ext_vector_type(8))) short bf16x8;
typedef __attribute__((ext_vector_type(4))) float f32x4;
typedef __attribute__((ext_vector_type(4))) unsigned short us4;
typedef __attribute__((ext_vector_type(8))) unsigned short us8;

__device__ __forceinline__ unsigned short f2bf(float f) {
  union { float f; unsigned u; } v; v.f = f;
  unsigned r = v.u + 0x7FFFu + ((v.u >> 16) & 1u);
  return (unsigned short)(r >> 16);
}

// ---------------- gating: one wave per token ----------------
__global__ void gate_kernel(const float* __restrict__ x, const float* __restrict__ gw,
                            int* __restrict__ counts, int* __restrict__ eids,
                            float* __restrict__ wts) {
  __shared__ int lc[E_NUM];
  const int tid = threadIdx.x;
  if (tid < E_NUM) lc[tid] = 0;
  __syncthreads();
  const int t = blockIdx.x * (blockDim.x >> 6) + (tid >> 6);
  const int lane = tid & 63;
  const float4* xr = (const float4*)(x + (size_t)t * H_DIM);
  float acc[E_NUM];
#pragma unroll
  for (int e = 0; e < E_NUM; ++e) acc[e] = 0.f;
#pragma unroll
  for (int j = 0; j < H_DIM / 256; ++j) {
    float4 xv = xr[lane + j * 64];
#pragma unroll
    for (int e = 0; e < E_NUM; ++e) {
      float4 gv = ((const float4*)(gw + (size_t)e * H_DIM))[lane + j * 64];
      acc[e] += xv.x * gv.x + xv.y * gv.y + xv.z * gv.z + xv.w * gv.w;
    }
  }
#pragma unroll
  for (int e = 0; e < E_NUM; ++e) {
    float v = acc[e];
    for (int off = 32; off > 0; off >>= 1) v += __shfl_xor(v, off, 64);
    acc[e] = v;
  }
  if (lane == 0) {
    float best = -1e30f, sec = -1e30f;
    int be = 0, se = 0;
#pragma unroll
    for (int e = 0; e < E_NUM; ++e) {
      float v = acc[e];
      if (v > best) { sec = best; se = be; best = v; be = e; }
      else if (v > sec) { sec = v; se = e; }
    }
    eids[2 * t] = be;
    eids[2 * t + 1] = se;
    float w0 = 1.f / (1.f + expf(sec - best));
    wts[2 * t] = w0;
    wts[2 * t + 1] = 1.f - w0;
    atomicAdd(&lc[be], 1);
    atomicAdd(&lc[se], 1);
  }
  __syncthreads();
  if (tid < E_NUM && lc[tid]) atomicAdd(&counts[tid], lc[tid]);
}

// ---------------- prefix scan over 8 experts ----------------
__global__ void scan_kernel(const int* __restrict__ counts, int* __restrict__ offsets,
                            int* __restrict__ cursors) {
  if (threadIdx.x == 0 && blockIdx.x == 0) {
    int s = 0;
    for (int e = 0; e < E_NUM; ++e) { offsets[e] = s; cursors[e] = s; s += counts[e]; }
  }
}

// ---------------- slot assignment ----------------
__global__ void assign_kernel(const int* __restrict__ eids, const float* __restrict__ wts,
                              int* __restrict__ cursors, int* __restrict__ tok_of_slot,
                              float* __restrict__ wslot) {
  __shared__ int lc[E_NUM], lb[E_NUM];
  const int tid = threadIdx.x;
  if (tid < E_NUM) lc[tid] = 0;
  __syncthreads();
  const int t = blockIdx.x * blockDim.x + tid;
  const int e0 = eids[2 * t], e1 = eids[2 * t + 1];
  const int p0 = atomicAdd(&lc[e0], 1);
  const int p1 = atomicAdd(&lc[e1], 1);
  __syncthreads();
  if (tid < E_NUM) lb[tid] = atomicAdd(&cursors[tid], lc[tid]);
  __syncthreads();
  const int s0 = lb[e0] + p0, s1 = lb[e1] + p1;
  tok_of_slot[s0] = t; wslot[s0] = wts[2 * t];
  tok_of_slot[s1] = t; wslot[s1] = wts[2 * t + 1];
}

// ---------------- grouped GEMM 1: x @ w1[e], fused swiglu -> act (bf16) ----------------
// block: 256 thr (4 waves), tile 128(M) x 128(N of F), dual B tiles (cols n and n+F), BK=32
__global__ __launch_bounds__(256, 2) void gemm_up(
    const float* __restrict__ x, const float* __restrict__ w1,
    const int* __restrict__ counts, const int* __restrict__ offsets,
    const int* __restrict__ tok_of_slot, unsigned short* __restrict__ act) {
  const int e = blockIdx.z;
  const int cnt = counts[e];
  const int m0 = blockIdx.y * 128;
  if (m0 >= cnt) return;
  const int base = offsets[e];
  const int nA = blockIdx.x * 128;

  __shared__ __align__(16) unsigned short As[128][40];
  __shared__ __align__(16) unsigned short Bs[2][128][40];

  const int tid = threadIdx.x;
  // A staging: chunk c = tid + 256*i -> row m=c>>3, k4=(c&7)*4
  const int ak = (tid & 7) * 4;
  const float* aptr[4];
#pragma unroll
  for (int i = 0; i < 4; ++i) {
    int sm = m0 + (tid >> 3) + 32 * i;
    if (sm > cnt - 1) sm = cnt - 1;  // clamp: dup row, store-masked later
    aptr[i] = x + (size_t)tok_of_slot[base + sm] * H_DIM + ak;
  }
  // B staging: thread owns col n=tid&127, k range 16*(tid>>7)..+15
  const int bn = tid & 127;
  const int bk = (tid >> 7) * 16;
  const float* wa = w1 + (size_t)e * H_DIM * (2 * F_DIM) + nA + bn;
  const float* wb = wa + F_DIM;

  const int lane = tid & 63;
  const int wv = tid >> 6;
  const int wr = (wv >> 1) * 64, wc = (wv & 1) * 64;
  const int fm = lane & 15, kq = lane >> 4;

  const f32x4 z = {0.f, 0.f, 0.f, 0.f};
  f32x4 acca[4][4], accb[4][4];
#pragma unroll
  for (int i = 0; i < 4; ++i)
#pragma unroll
    for (int j = 0; j < 4; ++j) { acca[i][j] = z; accb[i][j] = z; }

  for (int kt = 0; kt < H_DIM / 32; ++kt) {
    const int k0 = kt * 32;
#pragma unroll
    for (int i = 0; i < 4; ++i) {
      float4 v = *(const float4*)(aptr[i] + k0);
      us4 s; s.x = f2bf(v.x); s.y = f2bf(v.y); s.z = f2bf(v.z); s.w = f2bf(v.w);
      *(us4*)&As[(tid >> 3) + 32 * i][ak] = s;
    }
#pragma unroll
    for (int p = 0; p < 2; ++p) {
      const float* wp = p ? wb : wa;
#pragma unroll
      for (int q = 0; q < 4; ++q) {
        const int k = bk + q * 4;
        const size_t ro = (size_t)(k0 + k) * (2 * F_DIM);
        float v0 = wp[ro];
        float v1 = wp[ro + 2 * F_DIM];
        float v2 = wp[ro + 4 * F_DIM];
        float v3 = wp[ro + 6 * F_DIM];
        us4 s; s.x = f2bf(v0); s.y = f2bf(v1); s.z = f2bf(v2); s.w = f2bf(v3);
        *(us4*)&Bs[p][bn][k] = s;
      }
    }
    __syncthreads();
    bf16x8 af[4], bb[4];
#pragma unroll
    for (int i = 0; i < 4; ++i) af[i] = *(const bf16x8*)&As[wr + i * 16 + fm][kq * 8];
#pragma unroll
    for (int j = 0; j < 4; ++j) bb[j] = *(const bf16x8*)&Bs[0][wc + j * 16 + fm][kq * 8];
#pragma unroll
    for (int i = 0; i < 4; ++i)
#pragma unroll
      for (int j = 0; j < 4; ++j)
        acca[i][j] = __builtin_amdgcn_mfma_f32_16x16x32_bf16(af[i], bb[j], acca[i][j], 0, 0, 0);
#pragma unroll
    for (int j = 0; j < 4; ++j) bb[j] = *(const bf16x8*)&Bs[1][wc + j * 16 + fm][kq * 8];
#pragma unroll
    for (int i = 0; i < 4; ++i)
#pragma unroll
      for (int j = 0; j < 4; ++j)
        accb[i][j] = __builtin_amdgcn_mfma_f32_16x16x32_bf16(af[i], bb[j], accb[i][j], 0, 0, 0);
    __syncthreads();
  }

  // epilogue: act = silu(a) * b, bf16
#pragma unroll
  for (int i = 0; i < 4; ++i) {
#pragma unroll
    for (int r = 0; r < 4; ++r) {
      const int lm = wr + i * 16 + kq * 4 + r;
      const int sm = m0 + lm;
      if (sm >= cnt) continue;
      const size_t ro = (size_t)(base + sm) * F_DIM + nA + wc + fm;
#pragma unroll
      for (int j = 0; j < 4; ++j) {
        float a = acca[i][j][r];
        float b = accb[i][j][r];
        float s = a / (1.f + __expf(-a)) * b;
        act[ro + (size_t)j * 16] = f2bf(s);
      }
    }
  }
}

// ---------------- grouped GEMM 2: act @ w2[e] -> atomic scatter into out ----------------
__global__ __launch_bounds__(256, 2) void gemm_down(
    const unsigned short* __restrict__ act, const float* __restrict__ w2,
    const int* __restrict__ counts, const int* __restrict__ offsets,
    const int* __restrict__ tok_of_slot, const float* __restrict__ wslot,
    float* __restrict__ out) {
  const int e = blockIdx.z;
  const int cnt = counts[e];
  const int m0 = blockIdx.y * 128;
  if (m0 >= cnt) return;
  const int base = offsets[e];
  const int nB = blockIdx.x * 128;

  __shared__ __align__(16) unsigned short As[128][40];
  __shared__ __align__(16) unsigned short Bs[128][40];

  const int tid = threadIdx.x;
  const int ak8 = (tid & 3) * 8;
  const unsigned short* aptr[2];
#pragma unroll
  for (int i = 0; i < 2; ++i) {
    int sm = m0 + (tid >> 2) + 64 * i;
    if (sm > cnt - 1) sm = cnt - 1;
    aptr[i] = act + (size_t)(base + sm) * F_DIM + ak8;
  }
  const int bn = tid & 127;
  const int bk = (tid >> 7) * 16;
  const float* wp = w2 + (size_t)e * F_DIM * H_DIM + nB + bn;

  const int lane = tid & 63;
  const int wv = tid >> 6;
  const int wr = (wv >> 1) * 64, wc = (wv & 1) * 64;
  const int fm = lane & 15, kq = lane >> 4;

  const f32x4 z = {0.f, 0.f, 0.f, 0.f};
  f32x4 acc[4][4];
#pragma unroll
  for (int i = 0; i < 4; ++i)
#pragma unroll
    for (int j = 0; j < 4; ++j) acc[i][j] = z;

  for (int kt = 0; kt < F_DIM / 32; ++kt) {
    const int k0 = kt * 32;
#pragma unroll
    for (int i = 0; i < 2; ++i)
      *(us8*)&As[(tid >> 2) + 64 * i][ak8] = *(const us8*)(aptr[i] + k0);
#pragma unroll
    for (int q = 0; q < 4; ++q) {
      const int k = bk + q * 4;
      const size_t ro = (size_t)(k0 + k) * H_DIM;
      float v0 = wp[ro];
      float v1 = wp[ro + H_DIM];
      float v2 = wp[ro + 2 * H_DIM];
      float v3 = wp[ro + 3 * H_DIM];
      us4 s; s.x = f2bf(v0); s.y = f2bf(v1); s.z = f2bf(v2); s.w = f2bf(v3);
      *(us4*)&Bs[bn][k] = s;
    }
    __syncthreads();
    bf16x8 af[4], bb[4];
#pragma unroll
    for (int i = 0; i < 4; ++i) af[i] = *(const bf16x8*)&As[wr + i * 16 + fm][kq * 8];
#pragma unroll
    for (int j = 0; j < 4; ++j) bb[j] = *(const bf16x8*)&Bs[wc + j * 16 + fm][kq * 8];
#pragma unroll
    for (int i = 0; i < 4; ++i)
#pragma unroll
      for (int j = 0; j < 4; ++j)
        acc[i][j] = __builtin_amdgcn_mfma_f32_16x16x32_bf16(af[i], bb[j], acc[i][j], 0, 0, 0);
    __syncthreads();
  }

#pragma unroll
  for (int i = 0; i < 4; ++i) {
#pragma unroll
    for (int r = 0; r < 4; ++r) {
      const int lm = wr + i * 16 + kq * 4 + r;
      const int sm = m0 + lm;
      if (sm >= cnt) continue;
      const int slot = base + sm;
      const int tok = tok_of_slot[slot];
      const float wg = wslot[slot];
      float* orow = out + (size_t)tok * H_DIM + nB + wc + fm;
#pragma unroll
      for (int j = 0; j < 4; ++j)
        atomicAdd(&orow[j * 16], wg * acc[i][j][r]);
    }
  }
}

extern "C" void kernel_launch(void* const* d_in, const int* in_sizes, int n_in,
                              void* d_out, int out_size, void* d_ws, size_t ws_size,
                              hipStream_t stream) {
  const float* x  = (const float*)d_in[0];
  const float* gw = (const float*)d_in[1];
  const float* w1 = (const float*)d_in[2];
  const float* w2 = (const float*)d_in[3];
  float* out = (float*)d_out;
  char* ws = (char*)d_ws;

  // ws layout (needs ~67.4 MB)
  int*   counts      = (int*)(ws + 0);
  int*   offsets     = (int*)(ws + 64);
  int*   cursors     = (int*)(ws + 128);
  int*   eids        = (int*)(ws + 1024);    // 2T ints
  float* wts         = (float*)(ws + 65536); // 2T floats
  int*   tok_of_slot = (int*)(ws + 131072);  // 2T ints
  float* wslot       = (float*)(ws + 196608);// 2T floats
  unsigned short* act = (unsigned short*)(ws + 262144); // 8192 x 4096 bf16 = 64MB

  hipMemsetAsync(ws, 0, 256, stream);
  hipMemsetAsync(d_out, 0, (size_t)T_TOK * H_DIM * sizeof(float), stream);

  gate_kernel<<<T_TOK / 8, 512, 0, stream>>>(x, gw, counts, eids, wts);
  scan_kernel<<<1, 64, 0, stream>>>(counts, offsets, cursors);
  assign_kernel<<<T_TOK / 256, 256, 0, stream>>>(eids, wts, cursors, tok_of_slot, wslot);
  gemm_up<<<dim3(F_DIM / 128, T_TOK / 128, E_NUM), 256, 0, stream>>>(
      x, w1, counts, offsets, tok_of_slot, act);
  gemm_down<<<dim3(H_DIM / 128, T_TOK / 128, E_NUM), 256, 0, stream>>>(
      act, w2, counts, offsets, tok_of_slot, wslot, out);
}

// Round 2
// 1537.089 us; speedup vs baseline: 1.0463x; 1.0463x over previous
//
#include <hip/hip_runtime.h>

#define T_TOK 4096
#define H_DIM 2048
#define F_DIM 4096
#define E_NUM 8

typedef __attribute__((ext_vector_type(8))) short bf16x8;
typedef __attribute__((ext_vector_type(4))) float f32x4;
typedef __attribute__((ext_vector_type(4))) unsigned short us4;
typedef __attribute__((ext_vector_type(8))) unsigned short us8;

__device__ __forceinline__ unsigned short f2bf(float f) {
  union { float f; unsigned u; } v; v.f = f;
  unsigned r = v.u + 0x7FFFu + ((v.u >> 16) & 1u);
  return (unsigned short)(r >> 16);
}
__device__ __forceinline__ float bf2f(unsigned short s) {
  union { unsigned u; float f; } v; v.u = ((unsigned)s) << 16;
  return v.f;
}

#define GL2LDS16(g, l)                                                        \
  __builtin_amdgcn_global_load_lds(                                           \
      (__attribute__((address_space(1))) void*)(g),                           \
      (__attribute__((address_space(3))) void*)(l), 16, 0, 0)

// ---------------- gating: one wave per token ----------------
__global__ void gate_kernel(const float* __restrict__ x, const float* __restrict__ gw,
                            int* __restrict__ counts, int* __restrict__ eids,
                            float* __restrict__ wts) {
  __shared__ int lc[E_NUM];
  const int tid = threadIdx.x;
  if (tid < E_NUM) lc[tid] = 0;
  __syncthreads();
  const int t = blockIdx.x * (blockDim.x >> 6) + (tid >> 6);
  const int lane = tid & 63;
  const float4* xr = (const float4*)(x + (size_t)t * H_DIM);
  float acc[E_NUM];
#pragma unroll
  for (int e = 0; e < E_NUM; ++e) acc[e] = 0.f;
#pragma unroll
  for (int j = 0; j < H_DIM / 256; ++j) {
    float4 xv = xr[lane + j * 64];
#pragma unroll
    for (int e = 0; e < E_NUM; ++e) {
      float4 gv = ((const float4*)(gw + (size_t)e * H_DIM))[lane + j * 64];
      acc[e] += xv.x * gv.x + xv.y * gv.y + xv.z * gv.z + xv.w * gv.w;
    }
  }
#pragma unroll
  for (int e = 0; e < E_NUM; ++e) {
    float v = acc[e];
    for (int off = 32; off > 0; off >>= 1) v += __shfl_xor(v, off, 64);
    acc[e] = v;
  }
  if (lane == 0) {
    float best = -1e30f, sec = -1e30f;
    int be = 0, se = 0;
#pragma unroll
    for (int e = 0; e < E_NUM; ++e) {
      float v = acc[e];
      if (v > best) { sec = best; se = be; best = v; be = e; }
      else if (v > sec) { sec = v; se = e; }
    }
    eids[2 * t] = be;
    eids[2 * t + 1] = se;
    float w0 = 1.f / (1.f + expf(sec - best));
    wts[2 * t] = w0;
    wts[2 * t + 1] = 1.f - w0;
    atomicAdd(&lc[be], 1);
    atomicAdd(&lc[se], 1);
  }
  __syncthreads();
  if (tid < E_NUM && lc[tid]) atomicAdd(&counts[tid], lc[tid]);
}

// ---------------- prefix scan over 8 experts ----------------
__global__ void scan_kernel(const int* __restrict__ counts, int* __restrict__ offsets,
                            int* __restrict__ cursors) {
  if (threadIdx.x == 0 && blockIdx.x == 0) {
    int s = 0;
    for (int e = 0; e < E_NUM; ++e) { offsets[e] = s; cursors[e] = s; s += counts[e]; }
  }
}

// ---------------- slot assignment ----------------
__global__ void assign_kernel(const int* __restrict__ eids, const float* __restrict__ wts,
                              int* __restrict__ cursors, int* __restrict__ tok_of_slot,
                              float* __restrict__ wslot, int* __restrict__ slot_of_tok) {
  __shared__ int lc[E_NUM], lb[E_NUM];
  const int tid = threadIdx.x;
  if (tid < E_NUM) lc[tid] = 0;
  __syncthreads();
  const int t = blockIdx.x * blockDim.x + tid;
  const int e0 = eids[2 * t], e1 = eids[2 * t + 1];
  const int p0 = atomicAdd(&lc[e0], 1);
  const int p1 = atomicAdd(&lc[e1], 1);
  __syncthreads();
  if (tid < E_NUM) lb[tid] = atomicAdd(&cursors[tid], lc[tid]);
  __syncthreads();
  const int s0 = lb[e0] + p0, s1 = lb[e1] + p1;
  tok_of_slot[s0] = t; wslot[s0] = wts[2 * t];
  tok_of_slot[s1] = t; wslot[s1] = wts[2 * t + 1];
  slot_of_tok[2 * t] = s0; slot_of_tok[2 * t + 1] = s1;
}

// ---------------- fp32 -> bf16 flat convert (x) ----------------
__global__ void convert_x_kernel(const float* __restrict__ in, unsigned short* __restrict__ out) {
  const size_t i8 = ((size_t)blockIdx.x * blockDim.x + threadIdx.x) * 8;
  float4 a = *(const float4*)(in + i8);
  float4 b = *(const float4*)(in + i8 + 4);
  us8 o;
  o[0] = f2bf(a.x); o[1] = f2bf(a.y); o[2] = f2bf(a.z); o[3] = f2bf(a.w);
  o[4] = f2bf(b.x); o[5] = f2bf(b.y); o[6] = f2bf(b.z); o[7] = f2bf(b.w);
  *(us8*)(out + i8) = o;
}

// ---------------- fp32 [e][K][N] -> bf16 [e][N][K] transpose-convert ----------------
// 64x64 tiles. LDS tile row = 64 shorts (8 chunks of 16B), chunk q of row m
// stored at slot (q + m + (m>>2)) & 7  -> 2-way (free) write banks, b128 reads.
__global__ void transpose_cvt(const float* __restrict__ in, unsigned short* __restrict__ out,
                              int K, int N) {
  __shared__ __align__(16) unsigned short tile[64 * 64];
  const int e = blockIdx.z;
  const int n0 = blockIdx.x * 64;
  const int k0 = blockIdx.y * 64;
  const float* ib = in + (size_t)e * K * N;
  unsigned short* ob = out + (size_t)e * N * K;
  const int tid = threadIdx.x;
  const int c = (tid & 15) * 4;
#pragma unroll
  for (int pp = 0; pp < 2; ++pp) {
    const int P = (tid >> 4) + 16 * pp;  // k-pair index 0..31
    const int kk = 2 * P;
    float4 f0 = *(const float4*)(ib + (size_t)(k0 + kk) * N + n0 + c);
    float4 f1 = *(const float4*)(ib + (size_t)(k0 + kk + 1) * N + n0 + c);
    const float v0[4] = {f0.x, f0.y, f0.z, f0.w};
    const float v1[4] = {f1.x, f1.y, f1.z, f1.w};
    const int q = P >> 2, j = P & 3;
#pragma unroll
    for (int i = 0; i < 4; ++i) {
      const int m = c + i;
      const int slot = (q + m + (m >> 2)) & 7;
      unsigned pk = (unsigned)f2bf(v0[i]) | ((unsigned)f2bf(v1[i]) << 16);
      *(unsigned*)&tile[m * 64 + slot * 8 + j * 2] = pk;
    }
  }
  __syncthreads();
  const int n = tid >> 2;
#pragma unroll
  for (int qq = 0; qq < 2; ++qq) {
    const int q = 2 * (tid & 3) + qq;
    const int slot = (q + n + (n >> 2)) & 7;
    us8 v = *(const us8*)&tile[n * 64 + slot * 8];
    *(us8*)(ob + (size_t)(n0 + n) * K + k0 + q * 8) = v;
  }
}

// ======================= FAST PATH GEMMs (bf16, global_load_lds) =======================
// LDS tile layout: row r = 32 shorts (64 B) = 4 chunks of 16 B; global k-chunk g of
// row r stored at slot (g + (r>>1)) & 3. Staging lane l -> row base+(l>>2), slot l&3,
// fetches g = ((l&3) - (r>>1)) & 3. Frag read: offset r*32 + ((kq + (r>>1))&3)*8.

__global__ __launch_bounds__(256, 2) void gemm_up_f(
    const unsigned short* __restrict__ xb, const unsigned short* __restrict__ w1t,
    const int* __restrict__ counts, const int* __restrict__ offsets,
    const int* __restrict__ tok_of_slot, unsigned short* __restrict__ act) {
  const int e = blockIdx.z;
  const int cnt = counts[e];
  const int m0 = blockIdx.y * 128;
  if (m0 >= cnt) return;
  const int base = offsets[e];
  const int nA = blockIdx.x * 128;

  __shared__ __align__(16) unsigned short As[128 * 32];
  __shared__ __align__(16) unsigned short Bs[2][128 * 32];

  const int tid = threadIdx.x;
  const int wv = tid >> 6;
  const int lane = tid & 63;

  // A staging: wave wv -> rows [wv*32, wv*32+32), 2 instrs of 16 rows
  const unsigned short* aga[2];
  unsigned short* alds[2];
#pragma unroll
  for (int i = 0; i < 2; ++i) {
    const int r = wv * 32 + i * 16 + (lane >> 2);
    const int g = ((lane & 3) - (r >> 1)) & 3;
    int sm = m0 + r; if (sm > cnt - 1) sm = cnt - 1;
    aga[i] = xb + (size_t)tok_of_slot[base + sm] * H_DIM + g * 8;
    alds[i] = &As[(wv * 32 + i * 16) * 32];
  }
  // B staging: wave wv -> panel wv>>1, rows [(wv&1)*64, +64), 4 instrs
  const unsigned short* bga[4];
  unsigned short* blds[4];
  {
    const int p = wv >> 1;
#pragma unroll
    for (int i = 0; i < 4; ++i) {
      const int r = (wv & 1) * 64 + i * 16 + (lane >> 2);
      const int g = ((lane & 3) - (r >> 1)) & 3;
      const int ncol = nA + r + p * F_DIM;
      bga[i] = w1t + (size_t)e * (2 * F_DIM) * H_DIM + (size_t)ncol * H_DIM + g * 8;
      blds[i] = &Bs[p][((wv & 1) * 64 + i * 16) * 32];
    }
  }

  const int wr = (wv >> 1) * 64, wc = (wv & 1) * 64;
  const int fm = lane & 15, kq = lane >> 4;
  int aoff[4], boff[4];
#pragma unroll
  for (int i = 0; i < 4; ++i) {
    const int ra = wr + i * 16 + fm;
    aoff[i] = ra * 32 + ((kq + (ra >> 1)) & 3) * 8;
    const int rb = wc + i * 16 + fm;
    boff[i] = rb * 32 + ((kq + (rb >> 1)) & 3) * 8;
  }

  const f32x4 z = {0.f, 0.f, 0.f, 0.f};
  f32x4 acca[4][4], accb[4][4];
#pragma unroll
  for (int i = 0; i < 4; ++i)
#pragma unroll
    for (int j = 0; j < 4; ++j) { acca[i][j] = z; accb[i][j] = z; }

  for (int kt = 0; kt < H_DIM / 32; ++kt) {
    const int k0 = kt * 32;
#pragma unroll
    for (int i = 0; i < 2; ++i) GL2LDS16(aga[i] + k0, alds[i]);
#pragma unroll
    for (int i = 0; i < 4; ++i) GL2LDS16(bga[i] + k0, blds[i]);
    __syncthreads();
    bf16x8 af[4], bb[4];
#pragma unroll
    for (int i = 0; i < 4; ++i) af[i] = *(const bf16x8*)&As[aoff[i]];
#pragma unroll
    for (int j = 0; j < 4; ++j) bb[j] = *(const bf16x8*)&Bs[0][boff[j]];
#pragma unroll
    for (int i = 0; i < 4; ++i)
#pragma unroll
      for (int j = 0; j < 4; ++j)
        acca[i][j] = __builtin_amdgcn_mfma_f32_16x16x32_bf16(af[i], bb[j], acca[i][j], 0, 0, 0);
#pragma unroll
    for (int j = 0; j < 4; ++j) bb[j] = *(const bf16x8*)&Bs[1][boff[j]];
#pragma unroll
    for (int i = 0; i < 4; ++i)
#pragma unroll
      for (int j = 0; j < 4; ++j)
        accb[i][j] = __builtin_amdgcn_mfma_f32_16x16x32_bf16(af[i], bb[j], accb[i][j], 0, 0, 0);
    __syncthreads();
  }

#pragma unroll
  for (int i = 0; i < 4; ++i) {
#pragma unroll
    for (int r = 0; r < 4; ++r) {
      const int lm = wr + i * 16 + kq * 4 + r;
      const int sm = m0 + lm;
      if (sm >= cnt) continue;
      const size_t ro = (size_t)(base + sm) * F_DIM + nA + wc + fm;
#pragma unroll
      for (int j = 0; j < 4; ++j) {
        float a = acca[i][j][r];
        float b = accb[i][j][r];
        float s = a / (1.f + __expf(-a)) * b;
        act[ro + (size_t)j * 16] = f2bf(s);
      }
    }
  }
}

__global__ __launch_bounds__(256, 2) void gemm_down_f(
    const unsigned short* __restrict__ act, const unsigned short* __restrict__ w2t,
    const int* __restrict__ counts, const int* __restrict__ offsets,
    unsigned short* __restrict__ yslot) {
  const int e = blockIdx.z;
  const int cnt = counts[e];
  const int m0 = blockIdx.y * 128;
  if (m0 >= cnt) return;
  const int base = offsets[e];
  const int nB = blockIdx.x * 128;

  __shared__ __align__(16) unsigned short As[128 * 32];
  __shared__ __align__(16) unsigned short Bs[128 * 32];

  const int tid = threadIdx.x;
  const int wv = tid >> 6;
  const int lane = tid & 63;

  const unsigned short* aga[2];
  unsigned short* alds[2];
  const unsigned short* bga[2];
  unsigned short* blds[2];
#pragma unroll
  for (int i = 0; i < 2; ++i) {
    const int r = wv * 32 + i * 16 + (lane >> 2);
    const int g = ((lane & 3) - (r >> 1)) & 3;
    int sm = m0 + r; if (sm > cnt - 1) sm = cnt - 1;
    aga[i] = act + (size_t)(base + sm) * F_DIM + g * 8;
    alds[i] = &As[(wv * 32 + i * 16) * 32];
    bga[i] = w2t + (size_t)e * H_DIM * F_DIM + (size_t)(nB + r) * F_DIM + g * 8;
    blds[i] = &Bs[(wv * 32 + i * 16) * 32];
  }

  const int wr = (wv >> 1) * 64, wc = (wv & 1) * 64;
  const int fm = lane & 15, kq = lane >> 4;
  int aoff[4], boff[4];
#pragma unroll
  for (int i = 0; i < 4; ++i) {
    const int ra = wr + i * 16 + fm;
    aoff[i] = ra * 32 + ((kq + (ra >> 1)) & 3) * 8;
    const int rb = wc + i * 16 + fm;
    boff[i] = rb * 32 + ((kq + (rb >> 1)) & 3) * 8;
  }

  const f32x4 z = {0.f, 0.f, 0.f, 0.f};
  f32x4 acc[4][4];
#pragma unroll
  for (int i = 0; i < 4; ++i)
#pragma unroll
    for (int j = 0; j < 4; ++j) acc[i][j] = z;

  for (int kt = 0; kt < F_DIM / 32; ++kt) {
    const int k0 = kt * 32;
#pragma unroll
    for (int i = 0; i < 2; ++i) GL2LDS16(aga[i] + k0, alds[i]);
#pragma unroll
    for (int i = 0; i < 2; ++i) GL2LDS16(bga[i] + k0, blds[i]);
    __syncthreads();
    bf16x8 af[4], bb[4];
#pragma unroll
    for (int i = 0; i < 4; ++i) af[i] = *(const bf16x8*)&As[aoff[i]];
#pragma unroll
    for (int j = 0; j < 4; ++j) bb[j] = *(const bf16x8*)&Bs[boff[j]];
#pragma unroll
    for (int i = 0; i < 4; ++i)
#pragma unroll
      for (int j = 0; j < 4; ++j)
        acc[i][j] = __builtin_amdgcn_mfma_f32_16x16x32_bf16(af[i], bb[j], acc[i][j], 0, 0, 0);
    __syncthreads();
  }

#pragma unroll
  for (int i = 0; i < 4; ++i) {
#pragma unroll
    for (int r = 0; r < 4; ++r) {
      const int lm = wr + i * 16 + kq * 4 + r;
      const int sm = m0 + lm;
      if (sm >= cnt) continue;
      const size_t ro = (size_t)(base + sm) * H_DIM + nB + wc + fm;
#pragma unroll
      for (int j = 0; j < 4; ++j)
        yslot[ro + (size_t)j * 16] = f2bf(acc[i][j][r]);
    }
  }
}

// ---------------- combine: out[t] = w0*y[s0(t)] + w1*y[s1(t)] ----------------
__global__ void combine_kernel(const unsigned short* __restrict__ yslot,
                               const int* __restrict__ slot_of_tok,
                               const float* __restrict__ wslot, float* __restrict__ out) {
  const int t = blockIdx.x;
  const int c = threadIdx.x * 8;
  const int s0 = slot_of_tok[2 * t], s1 = slot_of_tok[2 * t + 1];
  const float w0 = wslot[s0], w1 = wslot[s1];
  us8 y0 = *(const us8*)(yslot + (size_t)s0 * H_DIM + c);
  us8 y1 = *(const us8*)(yslot + (size_t)s1 * H_DIM + c);
  float o[8];
#pragma unroll
  for (int i = 0; i < 8; ++i) o[i] = w0 * bf2f(y0[i]) + w1 * bf2f(y1[i]);
  float* op = out + (size_t)t * H_DIM + c;
  *(float4*)op = make_float4(o[0], o[1], o[2], o[3]);
  *(float4*)(op + 4) = make_float4(o[4], o[5], o[6], o[7]);
}

// ======================= FALLBACK GEMMs (round-1, fp32 weights) =======================
__global__ __launch_bounds__(256, 2) void gemm_up_s(
    const float* __restrict__ x, const float* __restrict__ w1,
    const int* __restrict__ counts, const int* __restrict__ offsets,
    const int* __restrict__ tok_of_slot, unsigned short* __restrict__ act) {
  const int e = blockIdx.z;
  const int cnt = counts[e];
  const int m0 = blockIdx.y * 128;
  if (m0 >= cnt) return;
  const int base = offsets[e];
  const int nA = blockIdx.x * 128;
  __shared__ __align__(16) unsigned short As[128][40];
  __shared__ __align__(16) unsigned short Bs[2][128][40];
  const int tid = threadIdx.x;
  const int ak = (tid & 7) * 4;
  const float* aptr[4];
#pragma unroll
  for (int i = 0; i < 4; ++i) {
    int sm = m0 + (tid >> 3) + 32 * i;
    if (sm > cnt - 1) sm = cnt - 1;
    aptr[i] = x + (size_t)tok_of_slot[base + sm] * H_DIM + ak;
  }
  const int bn = tid & 127;
  const int bk = (tid >> 7) * 16;
  const float* wa = w1 + (size_t)e * H_DIM * (2 * F_DIM) + nA + bn;
  const float* wb = wa + F_DIM;
  const int lane = tid & 63;
  const int wv = tid >> 6;
  const int wr = (wv >> 1) * 64, wc = (wv & 1) * 64;
  const int fm = lane & 15, kq = lane >> 4;
  const f32x4 z = {0.f, 0.f, 0.f, 0.f};
  f32x4 acca[4][4], accb[4][4];
#pragma unroll
  for (int i = 0; i < 4; ++i)
#pragma unroll
    for (int j = 0; j < 4; ++j) { acca[i][j] = z; accb[i][j] = z; }
  for (int kt = 0; kt < H_DIM / 32; ++kt) {
    const int k0 = kt * 32;
#pragma unroll
    for (int i = 0; i < 4; ++i) {
      float4 v = *(const float4*)(aptr[i] + k0);
      us4 s; s.x = f2bf(v.x); s.y = f2bf(v.y); s.z = f2bf(v.z); s.w = f2bf(v.w);
      *(us4*)&As[(tid >> 3) + 32 * i][ak] = s;
    }
#pragma unroll
    for (int p = 0; p < 2; ++p) {
      const float* wp = p ? wb : wa;
#pragma unroll
      for (int q = 0; q < 4; ++q) {
        const int k = bk + q * 4;
        const size_t ro = (size_t)(k0 + k) * (2 * F_DIM);
        float v0 = wp[ro];
        float v1 = wp[ro + 2 * F_DIM];
        float v2 = wp[ro + 4 * F_DIM];
        float v3 = wp[ro + 6 * F_DIM];
        us4 s; s.x = f2bf(v0); s.y = f2bf(v1); s.z = f2bf(v2); s.w = f2bf(v3);
        *(us4*)&Bs[p][bn][k] = s;
      }
    }
    __syncthreads();
    bf16x8 af[4], bb[4];
#pragma unroll
    for (int i = 0; i < 4; ++i) af[i] = *(const bf16x8*)&As[wr + i * 16 + fm][kq * 8];
#pragma unroll
    for (int j = 0; j < 4; ++j) bb[j] = *(const bf16x8*)&Bs[0][wc + j * 16 + fm][kq * 8];
#pragma unroll
    for (int i = 0; i < 4; ++i)
#pragma unroll
      for (int j = 0; j < 4; ++j)
        acca[i][j] = __builtin_amdgcn_mfma_f32_16x16x32_bf16(af[i], bb[j], acca[i][j], 0, 0, 0);
#pragma unroll
    for (int j = 0; j < 4; ++j) bb[j] = *(const bf16x8*)&Bs[1][wc + j * 16 + fm][kq * 8];
#pragma unroll
    for (int i = 0; i < 4; ++i)
#pragma unroll
      for (int j = 0; j < 4; ++j)
        accb[i][j] = __builtin_amdgcn_mfma_f32_16x16x32_bf16(af[i], bb[j], accb[i][j], 0, 0, 0);
    __syncthreads();
  }
#pragma unroll
  for (int i = 0; i < 4; ++i) {
#pragma unroll
    for (int r = 0; r < 4; ++r) {
      const int lm = wr + i * 16 + kq * 4 + r;
      const int sm = m0 + lm;
      if (sm >= cnt) continue;
      const size_t ro = (size_t)(base + sm) * F_DIM + nA + wc + fm;
#pragma unroll
      for (int j = 0; j < 4; ++j) {
        float a = acca[i][j][r];
        float b = accb[i][j][r];
        float s = a / (1.f + __expf(-a)) * b;
        act[ro + (size_t)j * 16] = f2bf(s);
      }
    }
  }
}

__global__ __launch_bounds__(256, 2) void gemm_down_s(
    const unsigned short* __restrict__ act, const float* __restrict__ w2,
    const int* __restrict__ counts, const int* __restrict__ offsets,
    const int* __restrict__ tok_of_slot, const float* __restrict__ wslot,
    float* __restrict__ out) {
  const int e = blockIdx.z;
  const int cnt = counts[e];
  const int m0 = blockIdx.y * 128;
  if (m0 >= cnt) return;
  const int base = offsets[e];
  const int nB = blockIdx.x * 128;
  __shared__ __align__(16) unsigned short As[128][40];
  __shared__ __align__(16) unsigned short Bs[128][40];
  const int tid = threadIdx.x;
  const int ak8 = (tid & 3) * 8;
  const unsigned short* aptr[2];
#pragma unroll
  for (int i = 0; i < 2; ++i) {
    int sm = m0 + (tid >> 2) + 64 * i;
    if (sm > cnt - 1) sm = cnt - 1;
    aptr[i] = act + (size_t)(base + sm) * F_DIM + ak8;
  }
  const int bn = tid & 127;
  const int bk = (tid >> 7) * 16;
  const float* wp = w2 + (size_t)e * F_DIM * H_DIM + nB + bn;
  const int lane = tid & 63;
  const int wv = tid >> 6;
  const int wr = (wv >> 1) * 64, wc = (wv & 1) * 64;
  const int fm = lane & 15, kq = lane >> 4;
  const f32x4 z = {0.f, 0.f, 0.f, 0.f};
  f32x4 acc[4][4];
#pragma unroll
  for (int i = 0; i < 4; ++i)
#pragma unroll
    for (int j = 0; j < 4; ++j) acc[i][j] = z;
  for (int kt = 0; kt < F_DIM / 32; ++kt) {
    const int k0 = kt * 32;
#pragma unroll
    for (int i = 0; i < 2; ++i)
      *(us8*)&As[(tid >> 2) + 64 * i][ak8] = *(const us8*)(aptr[i] + k0);
#pragma unroll
    for (int q = 0; q < 4; ++q) {
      const int k = bk + q * 4;
      const size_t ro = (size_t)(k0 + k) * H_DIM;
      float v0 = wp[ro];
      float v1 = wp[ro + H_DIM];
      float v2 = wp[ro + 2 * H_DIM];
      float v3 = wp[ro + 3 * H_DIM];
      us4 s; s.x = f2bf(v0); s.y = f2bf(v1); s.z = f2bf(v2); s.w = f2bf(v3);
      *(us4*)&Bs[bn][k] = s;
    }
    __syncthreads();
    bf16x8 af[4], bb[4];
#pragma unroll
    for (int i = 0; i < 4; ++i) af[i] = *(const bf16x8*)&As[wr + i * 16 + fm][kq * 8];
#pragma unroll
    for (int j = 0; j < 4; ++j) bb[j] = *(const bf16x8*)&Bs[wc + j * 16 + fm][kq * 8];
#pragma unroll
    for (int i = 0; i < 4; ++i)
#pragma unroll
      for (int j = 0; j < 4; ++j)
        acc[i][j] = __builtin_amdgcn_mfma_f32_16x16x32_bf16(af[i], bb[j], acc[i][j], 0, 0, 0);
    __syncthreads();
  }
#pragma unroll
  for (int i = 0; i < 4; ++i) {
#pragma unroll
    for (int r = 0; r < 4; ++r) {
      const int lm = wr + i * 16 + kq * 4 + r;
      const int sm = m0 + lm;
      if (sm >= cnt) continue;
      const int slot = base + sm;
      const int tok = tok_of_slot[slot];
      const float wg = wslot[slot];
      float* orow = out + (size_t)tok * H_DIM + nB + wc + fm;
#pragma unroll
      for (int j = 0; j < 4; ++j)
        atomicAdd(&orow[j * 16], wg * acc[i][j][r]);
    }
  }
}

extern "C" void kernel_launch(void* const* d_in, const int* in_sizes, int n_in,
                              void* d_out, int out_size, void* d_ws, size_t ws_size,
                              hipStream_t stream) {
  const float* x  = (const float*)d_in[0];
  const float* gw = (const float*)d_in[1];
  const float* w1 = (const float*)d_in[2];
  const float* w2 = (const float*)d_in[3];
  float* out = (float*)d_out;
  char* ws = (char*)d_ws;

  int*   counts      = (int*)(ws + 0);
  int*   offsets     = (int*)(ws + 64);
  int*   cursors     = (int*)(ws + 128);
  int*   eids        = (int*)(ws + 1024);
  float* wts         = (float*)(ws + 65536);
  int*   tok_of_slot = (int*)(ws + 131072);
  float* wslot       = (float*)(ws + 196608);
  int*   slot_of_tok = (int*)(ws + 229376);
  unsigned short* act = (unsigned short*)(ws + 262144);               // 64 MB
  unsigned short* xb    = (unsigned short*)(ws + 67371008);           // 16 MB
  unsigned short* yslot = (unsigned short*)(ws + 84148224);           // 32 MB
  unsigned short* w1t   = (unsigned short*)(ws + 117702656);          // 256 MB
  unsigned short* w2t   = (unsigned short*)(ws + 386138112);          // 128 MB
  const size_t NEED_FAST = 520355840;

  hipMemsetAsync(ws, 0, 1024, stream);

  gate_kernel<<<T_TOK / 8, 512, 0, stream>>>(x, gw, counts, eids, wts);
  scan_kernel<<<1, 64, 0, stream>>>(counts, offsets, cursors);
  assign_kernel<<<T_TOK / 256, 256, 0, stream>>>(eids, wts, cursors, tok_of_slot, wslot,
                                                 slot_of_tok);

  if (ws_size >= NEED_FAST) {
    convert_x_kernel<<<(T_TOK * H_DIM / 8) / 256, 256, 0, stream>>>(x, xb);
    transpose_cvt<<<dim3(2 * F_DIM / 64, H_DIM / 64, E_NUM), 256, 0, stream>>>(
        w1, w1t, H_DIM, 2 * F_DIM);
    transpose_cvt<<<dim3(H_DIM / 64, F_DIM / 64, E_NUM), 256, 0, stream>>>(
        w2, w2t, F_DIM, H_DIM);
    gemm_up_f<<<dim3(F_DIM / 128, T_TOK / 128, E_NUM), 256, 0, stream>>>(
        xb, w1t, counts, offsets, tok_of_slot, act);
    gemm_down_f<<<dim3(H_DIM / 128, T_TOK / 128, E_NUM), 256, 0, stream>>>(
        act, w2t, counts, offsets, yslot);
    combine_kernel<<<T_TOK, 256, 0, stream>>>(yslot, slot_of_tok, wslot, out);
  } else {
    hipMemsetAsync(d_out, 0, (size_t)T_TOK * H_DIM * sizeof(float), stream);
    gemm_up_s<<<dim3(F_DIM / 128, T_TOK / 128, E_NUM), 256, 0, stream>>>(
        x, w1, counts, offsets, tok_of_slot, act);
    gemm_down_s<<<dim3(H_DIM / 128, T_TOK / 128, E_NUM), 256, 0, stream>>>(
        act, w2, counts, offsets, tok_of_slot, wslot, out);
  }
}